// Round 3
// baseline (394.979 us; speedup 1.0000x reference)
//
#include <hip/hip_runtime.h>

#define EPS_K 1e-7f

typedef __attribute__((ext_vector_type(8)))  short          frag8;  // 8 bf16 (4 VGPRs)
typedef __attribute__((ext_vector_type(16))) float          accf16; // MFMA C/D
typedef __attribute__((ext_vector_type(4)))  unsigned short us4;    // 8B LDS read

__device__ __forceinline__ unsigned f2bf(float f) {
  union { float f; unsigned u; } v; v.f = f;
  unsigned u = v.u;
  u += 0x7FFFu + ((u >> 16) & 1u);   // RNE
  return u >> 16;
}
__device__ __forceinline__ float bf2f(unsigned short s) {
  union { unsigned u; float f; } v; v.u = ((unsigned)s) << 16;
  return v.f;
}
__device__ __forceinline__ unsigned pk_bf16(float lo, float hi) {
  return f2bf(lo) | (f2bf(hi) << 16);
}
__device__ __forceinline__ float rcp_f(float x) {
  return __builtin_amdgcn_rcpf(x);   // ~1 ulp; fine vs bf16 rounding floor
}

// ---------------------------------------------------------------------------
// Pre-pass: W (2048,32,32) f32 [s][t][u]  ->  Wbf bf16 [s][u][t] (4 MB in ws)
// ---------------------------------------------------------------------------
__global__ __launch_bounds__(256) void wbf_prep(
    const float* __restrict__ Wt, unsigned short* __restrict__ Wbf)
{
  __shared__ unsigned short tile[32 * 33];     // [t][u], pad 33
  const int s   = blockIdx.x;
  const int tid = threadIdx.x;
  {
    const int t  = tid >> 3;
    const int uc = tid & 7;                    // u-chunk of 4
    const float4 v = *(const float4*)(Wt + s * 1024 + t * 32 + 4 * uc);
    tile[t * 33 + 4 * uc + 0] = (unsigned short)f2bf(v.x);
    tile[t * 33 + 4 * uc + 1] = (unsigned short)f2bf(v.y);
    tile[t * 33 + 4 * uc + 2] = (unsigned short)f2bf(v.z);
    tile[t * 33 + 4 * uc + 3] = (unsigned short)f2bf(v.w);
  }
  __syncthreads();
  {
    const int u  = tid >> 3;
    const int tc = tid & 7;                    // t-chunk of 4
    uint2 d;
    d.x = (unsigned)tile[(4 * tc + 0) * 33 + u] | ((unsigned)tile[(4 * tc + 1) * 33 + u] << 16);
    d.y = (unsigned)tile[(4 * tc + 2) * 33 + u] | ((unsigned)tile[(4 * tc + 3) * 33 + u] << 16);
    *(uint2*)(Wbf + s * 1024 + u * 32 + 4 * tc) = d;  // lanes tc -> 64B contig
  }
}

// ---------------------------------------------------------------------------
// Main kernel, pipelined. 512 blocks (= 2/CU exactly, single generation) of
// 512 threads (8 waves). Each block: 8 subtiles of (8 s x 32 b), LDS double-
// buffered 2x16 KB. Subtile k covers s = k*256 + sq*8 + [0,8): interleaved so
// the 4 blocks sharing each 128B line (sq..sq+3, same bg, same XCD) stage it
// concurrently.
//
// Pipeline per k: compute(buf[k&1]) ; pack+ds_write(buf[(k+1)&1]) ;
// issue loads(k+2) ; lgkmcnt(0) + RAW s_barrier (no vmcnt drain -> loads
// stay in flight across the barrier; this is the whole point).
//
// Per-wave per-subtile: sl = wv (one s per wave). C layout (32x32 MFMA,
// HW-validated): col = lane&31 = b, row = (r&3)+8*(r>>2)+4*(lane>>5) = u.
// x-tile LDS layout unchanged: per-b 32 chunks of 8 bf16 (t-run, fixed s),
// chunk L = (t>>3)*8 + soff, swizzled L^(b&7).
// ---------------------------------------------------------------------------
template <bool WBF, bool USE_WS>
__global__ __launch_bounds__(512, 4) void attn_fused(
    const float* __restrict__ inp,
    const float* __restrict__ msk,
    const float* __restrict__ Wt,
    const unsigned short* __restrict__ Wbf,
    const float* __restrict__ bias,
    float* __restrict__ part,
    float* __restrict__ out)
{
  __shared__ unsigned short x_us[2][32 * 256];  // 2 x 16 KB

  const int tid = threadIdx.x;
  const int sq  = blockIdx.x >> 4;             // 0..31
  const int bg  = blockIdx.x & 15;             // 0..15

  // ---- staging decomposition: 512 thr = 32 b x 8 tq x 2 sc ----
  // thread owns rows t = 4*tq..4*tq+3, s-offsets 4*sc..4*sc+3 of each subtile
  const int b_s  = tid & 31;
  const int sc_s = (tid >> 5) & 1;
  const int tq_s = tid >> 6;                   // 0..7 (== wave id)
  const float* ip0 = inp + ((size_t)(bg * 32 + b_s) * 32 + 4 * tq_s) * 2048 + sq * 8 + 4 * sc_s;
  const float* mp0 = msk + ((size_t)(bg * 32 + b_s) * 32 + 4 * tq_s) * 2048 + sq * 8 + 4 * sc_s;

  float4 vi0, vi1, vi2, vi3, vm0, vm1, vm2, vm3;

#define STAGE_LOAD(k) do {                                                   \
    const float* ip = ip0 + (k) * 256;                                       \
    const float* mp = mp0 + (k) * 256;                                       \
    vi0 = *(const float4*)(ip);          vm0 = *(const float4*)(mp);         \
    vi1 = *(const float4*)(ip + 2048);   vm1 = *(const float4*)(mp + 2048);  \
    vi2 = *(const float4*)(ip + 4096);   vm2 = *(const float4*)(mp + 4096);  \
    vi3 = *(const float4*)(ip + 6144);   vm3 = *(const float4*)(mp + 6144);  \
  } while (0)

  // chunk L(w) = (tq>>1)*8 + 4*sc + w; elems 4*(tq&1)..+3 within chunk
#define STAGE_WRITE(k) do {                                                  \
    unsigned short* xb = &x_us[(k) & 1][0];                                  \
    _Pragma("unroll")                                                        \
    for (int w = 0; w < 4; ++w) {                                            \
      const int L = (tq_s >> 1) * 8 + 4 * sc_s + w;                          \
      uint2 d;                                                               \
      d.x = pk_bf16(((const float*)&vi0)[w] * ((const float*)&vm0)[w],       \
                    ((const float*)&vi1)[w] * ((const float*)&vm1)[w]);      \
      d.y = pk_bf16(((const float*)&vi2)[w] * ((const float*)&vm2)[w],       \
                    ((const float*)&vi3)[w] * ((const float*)&vm3)[w]);      \
      *(uint2*)(xb + b_s * 256 + ((L ^ (b_s & 7)) * 8) + 4 * (tq_s & 1)) = d;\
    }                                                                        \
  } while (0)

  // raw barrier: lgkmcnt(0) publishes ds_writes; NO vmcnt drain, so the
  // prefetch global loads stay in flight across the barrier.
#define SYNC do {                                                            \
    asm volatile("s_waitcnt lgkmcnt(0)" ::: "memory");                       \
    __builtin_amdgcn_s_barrier();                                            \
    asm volatile("" ::: "memory");                                           \
  } while (0)

  // ---- compute decomposition ----
  const int lane = tid & 63;
  const int wv   = tid >> 6;                   // wave 0..7 -> sl = wv
  const int n    = lane & 31;                  // b (B-frag n, C col) / u (A-frag m)
  const int h    = lane >> 5;                  // half-wave -> k-block / row group
  const int nx   = n & 7;

  float O[16];
  #pragma unroll
  for (int r = 0; r < 16; ++r) O[r] = 0.f;

  // ---- prologue ----
  STAGE_LOAD(0);
  STAGE_WRITE(0);
  STAGE_LOAD(1);
  SYNC;

  #pragma unroll
  for (int k = 0; k < 8; ++k) {
    const int s = k * 256 + sq * 8 + wv;
    const unsigned short* xb = &x_us[k & 1][0];

    // A-frag
    frag8 a1, a2;
    if (WBF) {
      const unsigned short* wp = Wbf + s * 1024 + n * 32 + 8 * h;
      a1 = *(const frag8*)(wp);
      a2 = *(const frag8*)(wp + 16);
    } else {
      const float* Wp = Wt + s * 1024;
      #pragma unroll
      for (int j = 0; j < 8; ++j) {
        const int t1 = 8 * h + j;
        a1[j] = (short)f2bf(Wp[t1 * 32 + n]);
        a2[j] = (short)f2bf(Wp[(t1 + 16) * 32 + n]);
      }
    }

    // B-frag: chunks L = h*8+wv (t=8h..8h+7) and (h+2)*8+wv (t=+16)
    const frag8 b1 = *(const frag8*)(xb + n * 256 + (((h      * 8 + wv) ^ nx) * 8));
    const frag8 b2 = *(const frag8*)(xb + n * 256 + ((((h + 2) * 8 + wv) ^ nx) * 8));

    // bias -> accumulator init (4 broadcast dwordx4)
    accf16 acc;
    #pragma unroll
    for (int g = 0; g < 4; ++g) {
      const float4 bb = *(const float4*)(bias + s * 32 + 8 * g + 4 * h);
      acc[4 * g + 0] = bb.x; acc[4 * g + 1] = bb.y;
      acc[4 * g + 2] = bb.z; acc[4 * g + 3] = bb.w;
    }
    acc = __builtin_amdgcn_mfma_f32_32x32x16_bf16(a1, b1, acc, 0, 0, 0);
    acc = __builtin_amdgcn_mfma_f32_32x32x16_bf16(a2, b2, acc, 0, 0, 0);

    // e = exp(tanh(z)); tanh(z) = 1 - 2/(exp(2z)+1); rcp instead of precise div
    float ps = 0.f;
    #pragma unroll
    for (int r = 0; r < 16; ++r) {
      const float z  = acc[r];
      const float e2 = __expf(2.f * z);
      const float th = 1.f - 2.f * rcp_f(e2 + 1.f);
      acc[r] = __expf(th);
      ps    += acc[r];
    }
    const float tot = ps + __shfl_xor(ps, 32, 64);
    const float inv = rcp_f(tot + EPS_K);

    // O += att * x ; x re-read as 4 x ds_read_b64 (u = 8g+4h+i -> r = 4g+i)
    #pragma unroll
    for (int g = 0; g < 4; ++g) {
      const us4 xv = *(const us4*)(xb + n * 256 + (((g * 8 + wv) ^ nx) * 8) + 4 * h);
      #pragma unroll
      for (int i = 0; i < 4; ++i)
        O[4 * g + i] += acc[4 * g + i] * inv * bf2f(xv[i]);
    }

    // ---- pipeline: publish next tile, issue tile after next ----
    if (k < 7) {
      STAGE_WRITE(k + 1);                      // waits vmcnt on loads(k+1) only
      if (k < 6) STAGE_LOAD(k + 2);            // in flight across SYNC
      SYNC;
    }
  }

  // ---- cross-wave reduction in LDS (8 waves x 1024 f32 = 32 KB, reuse) ----
  __syncthreads();
  float* red = (float*)&x_us[0][0];
  #pragma unroll
  for (int r = 0; r < 16; ++r) {
    const int u = (r & 3) + 8 * (r >> 2) + 4 * h;
    red[wv * 1024 + n * 32 + (u ^ n)] = O[r];
  }
  __syncthreads();

  const int q0 = tid * 2;                      // 512 threads x 2 outputs
  float2 v;
  #pragma unroll
  for (int i = 0; i < 2; ++i) {
    const int q = q0 + i;
    const int b = q >> 5, u = q & 31;
    float sum = 0.f;
    #pragma unroll
    for (int w = 0; w < 8; ++w) sum += red[w * 1024 + b * 32 + (u ^ b)];
    (&v.x)[i] = sum;
  }
  if (USE_WS) {
    *(float2*)(part + (size_t)sq * 16384 + bg * 1024 + q0) = v;
  } else {
    float* op = out + bg * 1024 + q0;
    atomicAdd(op + 0, v.x);
    atomicAdd(op + 1, v.y);
  }

#undef STAGE_LOAD
#undef STAGE_WRITE
#undef SYNC
}

// out[f] = sum over 32 s-groups of part[sqg][f]
__global__ __launch_bounds__(256) void reduce_part(
    const float* __restrict__ part, float* __restrict__ out)
{
  const int f = blockIdx.x * 256 + threadIdx.x;
  float s = 0.f;
  #pragma unroll 8
  for (int sq = 0; sq < 32; ++sq) s += part[(size_t)sq * 16384 + f];
  out[f] = s;
}

extern "C" void kernel_launch(void* const* d_in, const int* in_sizes, int n_in,
                              void* d_out, int out_size, void* d_ws, size_t ws_size,
                              hipStream_t stream) {
  const float* inp  = (const float*)d_in[0];   // (512,32,2048) f32
  const float* msk  = (const float*)d_in[1];   // (512,32,2048) f32
  const float* Wt   = (const float*)d_in[2];   // (2048,32,32)  f32
  const float* bias = (const float*)d_in[3];   // (2048,32)     f32
  float* out = (float*)d_out;                  // (512,32)      f32

  const size_t part_sz = (size_t)32 * 16384 * sizeof(float);           // 2 MB
  const size_t wbf_sz  = (size_t)2048 * 1024 * sizeof(unsigned short); // 4 MB

  if (ws_size >= part_sz + wbf_sz) {
    float* part = (float*)d_ws;
    unsigned short* Wbf = (unsigned short*)((char*)d_ws + part_sz);
    wbf_prep<<<dim3(2048), dim3(256), 0, stream>>>(Wt, Wbf);
    attn_fused<true, true><<<dim3(512), dim3(512), 0, stream>>>(
        inp, msk, Wt, Wbf, bias, part, out);
    reduce_part<<<dim3(64), dim3(256), 0, stream>>>(part, out);
  } else if (ws_size >= part_sz) {
    float* part = (float*)d_ws;
    attn_fused<false, true><<<dim3(512), dim3(512), 0, stream>>>(
        inp, msk, Wt, nullptr, bias, part, out);
    reduce_part<<<dim3(64), dim3(256), 0, stream>>>(part, out);
  } else {
    (void)hipMemsetAsync(out, 0, (size_t)out_size * sizeof(float), stream);
    attn_fused<false, false><<<dim3(512), dim3(512), 0, stream>>>(
        inp, msk, Wt, nullptr, bias, nullptr, out);
  }
}

// Round 4
// 322.389 us; speedup vs baseline: 1.2252x; 1.2252x over previous
//
#include <hip/hip_runtime.h>

#define EPS_K 1e-7f

typedef __attribute__((ext_vector_type(8)))  short          frag8;  // 8 bf16 (4 VGPRs)
typedef __attribute__((ext_vector_type(16))) float          accf16; // MFMA C/D
typedef __attribute__((ext_vector_type(4)))  unsigned short us4;    // 8B LDS read
typedef __attribute__((ext_vector_type(4)))  float          f32x4;

__device__ __forceinline__ unsigned f2bf(float f) {
  union { float f; unsigned u; } v; v.f = f;
  unsigned u = v.u;
  u += 0x7FFFu + ((u >> 16) & 1u);   // RNE
  return u >> 16;
}
__device__ __forceinline__ float bf2f(unsigned short s) {
  union { unsigned u; float f; } v; v.u = ((unsigned)s) << 16;
  return v.f;
}
__device__ __forceinline__ unsigned pk_bf16(float lo, float hi) {
  return f2bf(lo) | (f2bf(hi) << 16);
}
__device__ __forceinline__ float rcp_f(float x) {
  return __builtin_amdgcn_rcpf(x);   // validated: absmax unchanged (round 3)
}

// ---------------------------------------------------------------------------
// Pre-pass: W (2048,32,32) f32 [s][t][u]  ->  Wbf bf16 [s][u][t] (4 MB in ws)
// ---------------------------------------------------------------------------
__global__ __launch_bounds__(256) void wbf_prep(
    const float* __restrict__ Wt, unsigned short* __restrict__ Wbf)
{
  __shared__ unsigned short tile[32 * 33];     // [t][u], pad 33
  const int s   = blockIdx.x;
  const int tid = threadIdx.x;
  {
    const int t  = tid >> 3;
    const int uc = tid & 7;
    const float4 v = *(const float4*)(Wt + s * 1024 + t * 32 + 4 * uc);
    tile[t * 33 + 4 * uc + 0] = (unsigned short)f2bf(v.x);
    tile[t * 33 + 4 * uc + 1] = (unsigned short)f2bf(v.y);
    tile[t * 33 + 4 * uc + 2] = (unsigned short)f2bf(v.z);
    tile[t * 33 + 4 * uc + 3] = (unsigned short)f2bf(v.w);
  }
  __syncthreads();
  {
    const int u  = tid >> 3;
    const int tc = tid & 7;
    uint2 d;
    d.x = (unsigned)tile[(4 * tc + 0) * 33 + u] | ((unsigned)tile[(4 * tc + 1) * 33 + u] << 16);
    d.y = (unsigned)tile[(4 * tc + 2) * 33 + u] | ((unsigned)tile[(4 * tc + 3) * 33 + u] << 16);
    *(uint2*)(Wbf + s * 1024 + u * 32 + 4 * tc) = d;
  }
}

// ---------------------------------------------------------------------------
// Main kernel: persistent 4-tile blocks with a 16-phase software pipeline.
//
// Grid 512 = 128 st x 4 bgq  (blockIdx = bgq*128 + st so the 4 blocks sharing
// an st/W-slice sit on the SAME XCD). 256 threads (4 waves). Block handles
// tiles ti=0..3: tile = (st, bg = bgq*4+ti), 16 s x 32 b, identical layout
// math to the verified round-0 kernel.
//
// Pipeline, global phase gp = ti*4+p (p = wave's s-index within tile):
//   load@gp  : b-chunk (8 b x 32 t x 16 s raw, 8 float4/thread, set p&1)
//              for phase gp+5 (next tile, chunk p+1 mod 4)
//   write@gp : pack+ds_write the set loaded @gp-1 (covers phase gp+4)
//   -> every chunk of tile ti+1 is in LDS before the tile boundary; each
//      load has a full phase (~1000 cy) of compute to hide under; the only
//      vmcnt waits are vmcnt(8) inside WRITEX. No per-phase barriers.
// Tile boundary: 3 lgkm-only raw barriers (reduction reuses the consumed
// x-buffer; in-flight prefetch loads survive all barriers).
//
// W fragments (a1/a2 for all 4 phases) + bias are st-only -> hoisted once
// per block (also cuts W traffic 4x vs per-tile blocks).
// LDS: 2x32KB x-dbuf + 2KB bias = 66KB -> exactly 2 blocks/CU.
// __launch_bounds__(256,2): VGPR cap 256 under either arg2 semantics -> the
// ~64 VGPR of in-flight staging regs cannot force a spill (round-3 lesson).
// ---------------------------------------------------------------------------
template <bool WBF, bool USE_WS>
__global__ __launch_bounds__(256, 2) void attn_fused(
    const float* __restrict__ inp,
    const float* __restrict__ msk,
    const float* __restrict__ Wt,
    const unsigned short* __restrict__ Wbf,
    const float* __restrict__ bias,
    float* __restrict__ part,
    float* __restrict__ out)
{
  __shared__ unsigned short x_us[2][32 * 512];  // 2 x 32 KB
  __shared__ float bias_sm[512];                // 2 KB

  const int tid = threadIdx.x;
  const int st  = blockIdx.x & 127;
  const int bgq = blockIdx.x >> 7;              // 0..3
  const int s0  = st * 16;

  // staging coords: thread owns (b-in-chunk bq, t = 4tq..4tq+3, s = 4sc..+3)
  const int sc = tid & 3;
  const int tq = (tid >> 2) & 7;
  const int bq = tid >> 5;                      // 0..7

  // compute coords
  const int lane = tid & 63;
  const int wv   = tid >> 6;                    // 0..3
  const int n    = lane & 31;
  const int h    = lane >> 5;
  const int nx   = n & 7;

  // bias -> LDS (contiguous 512 f32 for this st)
  *(float2*)(bias_sm + 2 * tid) = *(const float2*)(bias + st * 512 + 2 * tid);

  // A-frags for all 4 phases (st-only -> load once, reuse across 4 tiles)
  frag8 a1[4], a2[4];
  if (WBF) {
    #pragma unroll
    for (int p = 0; p < 4; ++p) {
      const unsigned short* wp = Wbf + (size_t)(s0 + wv * 4 + p) * 1024 + n * 32 + 8 * h;
      a1[p] = *(const frag8*)(wp);
      a2[p] = *(const frag8*)(wp + 16);
    }
  } else {
    #pragma unroll
    for (int p = 0; p < 4; ++p) {
      const float* Wp = Wt + (size_t)(s0 + wv * 4 + p) * 1024;
      #pragma unroll
      for (int j = 0; j < 8; ++j) {
        a1[p][j] = (short)f2bf(Wp[(8 * h + j) * 32 + n]);
        a2[p][j] = (short)f2bf(Wp[(8 * h + j + 16) * 32 + n]);
      }
    }
  }

  f32x4 viA0, viA1, viA2, viA3, vmA0, vmA1, vmA2, vmA3;
  f32x4 viB0, viB1, viB2, viB3, vmB0, vmB1, vmB2, vmB3;

#define LOADX(S, ph) do {                                                     \
    const int ti_ = (ph) >> 2, ck_ = (ph) & 3;                                \
    const size_t ro_ = ((size_t)((bgq * 4 + ti_) * 32 + 8 * ck_ + bq) * 32    \
                       + 4 * tq) * 2048 + s0 + 4 * sc;                        \
    const float* ip_ = inp + ro_;                                             \
    const float* mp_ = msk + ro_;                                             \
    vi##S##0 = *(const f32x4*)(ip_);        vm##S##0 = *(const f32x4*)(mp_);  \
    vi##S##1 = *(const f32x4*)(ip_ + 2048); vm##S##1 = *(const f32x4*)(mp_ + 2048); \
    vi##S##2 = *(const f32x4*)(ip_ + 4096); vm##S##2 = *(const f32x4*)(mp_ + 4096); \
    vi##S##3 = *(const f32x4*)(ip_ + 6144); vm##S##3 = *(const f32x4*)(mp_ + 6144); \
  } while (0)

#define WRITEX(S, ph) do {                                                    \
    const int ti_ = (ph) >> 2, ck_ = (ph) & 3;                                \
    const int b_ = 8 * ck_ + bq;                                              \
    unsigned short* xb_ = &x_us[ti_ & 1][0] + b_ * 512 + 4 * (tq & 1);        \
    _Pragma("unroll")                                                         \
    for (int w = 0; w < 4; ++w) {                                             \
      const int L_ = (tq >> 1) * 16 + 4 * sc + w;                             \
      uint2 d_;                                                               \
      d_.x = pk_bf16(vi##S##0[w] * vm##S##0[w], vi##S##1[w] * vm##S##1[w]);   \
      d_.y = pk_bf16(vi##S##2[w] * vm##S##2[w], vi##S##3[w] * vm##S##3[w]);   \
      *(uint2*)(xb_ + (L_ ^ (b_ & 7)) * 8) = d_;                              \
    }                                                                         \
  } while (0)

  // lgkm-only barrier: publishes ds_writes, keeps global loads IN FLIGHT.
#define SYNC do {                                                             \
    asm volatile("s_waitcnt lgkmcnt(0)" ::: "memory");                        \
    __builtin_amdgcn_s_barrier();                                             \
    asm volatile("" ::: "memory");                                            \
  } while (0)

  float O[16];
  #pragma unroll
  for (int r = 0; r < 16; ++r) O[r] = 0.f;

  // ---- prologue: stage tile 0 (phases 0..3) + load phase-4 chunk into B ----
  LOADX(A, 0); LOADX(B, 1); WRITEX(A, 0);
  LOADX(A, 2); WRITEX(B, 1);
  LOADX(B, 3); WRITEX(A, 2); WRITEX(B, 3);
  LOADX(B, 4);
  SYNC;

  // ---- main loop: 4 tiles x 4 phases; p unrolled (static sets / a[p]) ----
#define PHASE(P, SL, SW) do {                                                 \
    const int ph_l = ti * 4 + (P) + 5;                                        \
    if (ph_l < 16) LOADX(SL, ph_l);                                           \
    const int ph_w = ti * 4 + (P) + 4;                                        \
    if (ph_w < 16) WRITEX(SW, ph_w);                                          \
    const int sl = wv * 4 + (P);                                              \
    const unsigned short* xb = &x_us[ti & 1][0];                              \
    const frag8 b1 = *(const frag8*)(xb + n * 512 + (((h    ) * 16 + sl) ^ nx) * 8); \
    const frag8 b2 = *(const frag8*)(xb + n * 512 + (((h + 2) * 16 + sl) ^ nx) * 8); \
    accf16 acc;                                                               \
    _Pragma("unroll")                                                         \
    for (int g = 0; g < 4; ++g) {                                             \
      const f32x4 bb = *(const f32x4*)(bias_sm + sl * 32 + 8 * g + 4 * h);    \
      acc[4 * g + 0] = bb[0]; acc[4 * g + 1] = bb[1];                         \
      acc[4 * g + 2] = bb[2]; acc[4 * g + 3] = bb[3];                         \
    }                                                                         \
    acc = __builtin_amdgcn_mfma_f32_32x32x16_bf16(a1[(P)], b1, acc, 0, 0, 0); \
    acc = __builtin_amdgcn_mfma_f32_32x32x16_bf16(a2[(P)], b2, acc, 0, 0, 0); \
    float ps = 0.f;                                                           \
    _Pragma("unroll")                                                         \
    for (int r = 0; r < 16; ++r) {                                            \
      const float z  = acc[r];                                                \
      const float e2 = __expf(2.f * z);                                       \
      const float th = 1.f - 2.f * rcp_f(e2 + 1.f);                           \
      acc[r] = __expf(th);                                                    \
      ps    += acc[r];                                                        \
    }                                                                         \
    const float tot = ps + __shfl_xor(ps, 32, 64);                            \
    const float inv = rcp_f(tot + EPS_K);                                     \
    _Pragma("unroll")                                                         \
    for (int g = 0; g < 4; ++g) {                                             \
      const us4 xv = *(const us4*)(xb + n * 512 + (((g * 16 + sl) ^ nx) * 8) + 4 * h); \
      _Pragma("unroll")                                                       \
      for (int i = 0; i < 4; ++i)                                             \
        O[4 * g + i] += acc[4 * g + i] * inv * bf2f(xv[i]);                   \
    }                                                                         \
  } while (0)

  #pragma unroll 1
  for (int ti = 0; ti < 4; ++ti) {
    PHASE(0, A, B);
    PHASE(1, B, A);
    PHASE(2, A, B);
    PHASE(3, B, A);

    // ---- tile epilogue: cross-wave reduce in the just-consumed buffer ----
    SYNC;                                       // all reads of buf[ti&1] done
    float* red = (float*)&x_us[ti & 1][0];      // 16 KB scratch
    #pragma unroll
    for (int r = 0; r < 16; ++r) {
      const int u = (r & 3) + 8 * (r >> 2) + 4 * h;
      red[wv * 1024 + n * 32 + (u ^ n)] = O[r];
      O[r] = 0.f;
    }
    SYNC;                                       // publish partials
    const int q0 = tid * 4;
    f32x4 v;
    #pragma unroll
    for (int i = 0; i < 4; ++i) {
      const int q = q0 + i;
      const int b = q >> 5, u = q & 31;
      float sum = 0.f;
      #pragma unroll
      for (int w = 0; w < 4; ++w) sum += red[w * 1024 + b * 32 + (u ^ b)];
      v[i] = sum;
    }
    const int bg = bgq * 4 + ti;
    if (USE_WS) {
      *(f32x4*)(part + (size_t)st * 16384 + bg * 1024 + q0) = v;
    } else {
      float* op = out + bg * 1024 + q0;
      #pragma unroll
      for (int i = 0; i < 4; ++i) atomicAdd(op + i, v[i]);
    }
    SYNC;                                       // red free before next reuse
  }

#undef PHASE
#undef LOADX
#undef WRITEX
#undef SYNC
}

// out[f] = sum over 128 s-tiles of part[st][f]
__global__ __launch_bounds__(256) void reduce_part(
    const float* __restrict__ part, float* __restrict__ out)
{
  const int f = blockIdx.x * 256 + threadIdx.x;
  float s = 0.f;
  #pragma unroll 8
  for (int st = 0; st < 128; ++st) s += part[(size_t)st * 16384 + f];
  out[f] = s;
}

extern "C" void kernel_launch(void* const* d_in, const int* in_sizes, int n_in,
                              void* d_out, int out_size, void* d_ws, size_t ws_size,
                              hipStream_t stream) {
  const float* inp  = (const float*)d_in[0];   // (512,32,2048) f32
  const float* msk  = (const float*)d_in[1];   // (512,32,2048) f32
  const float* Wt   = (const float*)d_in[2];   // (2048,32,32)  f32
  const float* bias = (const float*)d_in[3];   // (2048,32)     f32
  float* out = (float*)d_out;                  // (512,32)      f32

  const size_t part_sz = (size_t)128 * 16384 * sizeof(float);          // 8 MB
  const size_t wbf_sz  = (size_t)2048 * 1024 * sizeof(unsigned short); // 4 MB

  if (ws_size >= part_sz + wbf_sz) {
    float* part = (float*)d_ws;
    unsigned short* Wbf = (unsigned short*)((char*)d_ws + part_sz);
    wbf_prep<<<dim3(2048), dim3(256), 0, stream>>>(Wt, Wbf);
    attn_fused<true, true><<<dim3(512), dim3(256), 0, stream>>>(
        inp, msk, Wt, Wbf, bias, part, out);
    reduce_part<<<dim3(64), dim3(256), 0, stream>>>(part, out);
  } else if (ws_size >= part_sz) {
    float* part = (float*)d_ws;
    attn_fused<false, true><<<dim3(512), dim3(256), 0, stream>>>(
        inp, msk, Wt, nullptr, bias, part, out);
    reduce_part<<<dim3(64), dim3(256), 0, stream>>>(part, out);
  } else {
    (void)hipMemsetAsync(out, 0, (size_t)out_size * sizeof(float), stream);
    attn_fused<false, false><<<dim3(512), dim3(256), 0, stream>>>(
        inp, msk, Wt, nullptr, bias, nullptr, out);
  }
}